// Round 7
// baseline (11685.792 us; speedup 1.0000x reference)
//
#include <hip/hip_runtime.h>
#include <hip/hip_bf16.h>
#include <stdint.h>
#include <stddef.h>

#define TPAD 320   // padded time stride (300 real + 20 pad)
#define TREAL 300

// Python-f64 constants (exactly what a numpy mirror of the reference uses)
#define POOL_W   11.000000000000002    // float(1.1*10.0)
#define REF_DEC  0.36787944117144233   // float(np.exp(-1.0))

static __device__ __forceinline__ float bf2f(uint16_t b) {
    return __uint_as_float(((uint32_t)b) << 16);
}
static __device__ __forceinline__ float bcvt(uint32_t u, int j) {
    return (float)((u >> (8 * j)) & 0xffu);
}

// ---------------------------------------------------------------------------
// Dtype detection (bf16 vs f32) from W1's first 800 uint16 halves.
// (bf16 confirmed by round-5 marker readback; f32 path kept as fallback.)
// ---------------------------------------------------------------------------
__global__ void detect_kernel(const uint16_t* __restrict__ w1raw, int* __restrict__ flag)
{
    if (threadIdx.x == 0 && blockIdx.x == 0) {
        int sane = 1;
        for (int i = 0; i < 800; ++i) {
            int e = (w1raw[i] >> 7) & 0xFF;
            if (e >= 131) { sane = 0; break; }
        }
        *flag = sane;   // 1 = bf16, 0 = f32
    }
}

// ---------------------------------------------------------------------------
// EPS taps in f64: eps[k] = (k/10)*exp(1 - k/10), elementwise f64 like numpy.
// ---------------------------------------------------------------------------
__global__ void eps_kernel(double* __restrict__ epsd)
{
    int k = threadIdx.x;
    if (k < 100) {
        double q = (double)k / 10.0;
        epsd[k] = q * exp(1.0 - q);
    }
}

// ---------------------------------------------------------------------------
// Weight convert -> f32 ws copy (bf16->f32 is EXACT; f64 upconvert at use)
// ---------------------------------------------------------------------------
__global__ __launch_bounds__(256) void wcvt_kernel(
    const void* __restrict__ w, float* __restrict__ out, int n, const int* __restrict__ flag)
{
    int i = blockIdx.x * 256 + threadIdx.x;
    if (i >= n) return;
    out[i] = (*flag) ? bf2f(((const uint16_t*)w)[i]) : ((const float*)w)[i];
}

// ---------------------------------------------------------------------------
// Input (binary 0/1) -> uint8 spikes in TPAD layout (pad zeroed)
// ---------------------------------------------------------------------------
__global__ __launch_bounds__(320) void convert_kernel(
    const void* __restrict__ s_in, uint8_t* __restrict__ u8, const int* __restrict__ flag)
{
    int row = blockIdx.x;
    int t = threadIdx.x;
    uint8_t v = 0;
    if (t < TREAL) {
        float x = (*flag) ? bf2f(((const uint16_t*)s_in)[(size_t)row * TREAL + t])
                          : ((const float*)s_in)[(size_t)row * TREAL + t];
        v = (x >= 0.5f) ? 1 : 0;
    }
    u8[(size_t)row * TPAD + t] = v;
}

// ---------------------------------------------------------------------------
// Spatial conv at every t. f64 accumulation (EXACT for bf16 weights x {0,1}
// spikes -> order-independent, bit-equal to np f64). z stored f64.
// ---------------------------------------------------------------------------
template<int Ci, int CIB, int CoB, int K, int Hi, int Wi, int CPS, int WUN, int NWSPLIT>
__global__ __launch_bounds__(256) void conv_kernel(
    const uint8_t* __restrict__ sprev,  // [Bg][Ci][Hi][Wi][TPAD]
    const float* __restrict__ Wg,       // [Co_total][Ci][K][K] (f32 = exact bf16)
    double* __restrict__ z,             // [Bg][Co_total][Ho][Wo][TPAD]
    int Co_total)
{
    static_assert(CoB == 16 * CPS, "slot layout");
    constexpr int P = 1;
    constexpr int Ho = Hi + 2 * P - K + 1;
    constexpr int Wo = Wi + 2 * P - K + 1;
    constexpr int Wp = Wi + 2 * P;
    constexpr int CKK = Ci * K * K;
    constexpr int WoS = Wo / NWSPLIT;
    constexpr int NCB = Ci / CIB;
    static_assert(Wo % NWSPLIT == 0 && WoS % WUN == 0 && Ci % CIB == 0, "split");

    __shared__ uint32_t in_lds[CIB][K][Wp][16];
    __shared__ float w_lds[CoB][CKK + 1];
    static_assert(sizeof(in_lds) + sizeof(w_lds) <= 60 * 1024, "LDS over limit");

    const int tid = threadIdx.x;
    const int h   = blockIdx.x;
    const int wsp = (int)blockIdx.y % NWSPLIT;
    const int co0 = ((int)blockIdx.y / NWSPLIT) * CoB;
    const int b   = blockIdx.z;
    const int wbase = wsp * WoS;

    for (int i = tid; i < CoB * CKK; i += 256) {
        int co = i / CKK, rest = i - co * CKK;
        w_lds[co][rest] = Wg[(size_t)(co0 + co) * CKK + rest];
    }

    const int slot = tid >> 4;
    const int tl   = tid & 15;
    const size_t in_b = (size_t)b * Ci * Hi * Wi * TPAD;

    for (int tc = 0; tc < 5; ++tc) {
        double acc[CPS][WoS][4];
        #pragma unroll
        for (int c = 0; c < CPS; ++c)
            #pragma unroll
            for (int w = 0; w < WoS; ++w)
                #pragma unroll
                for (int q = 0; q < 4; ++q) acc[c][w][q] = 0.0;

        for (int cb = 0; cb < NCB; ++cb) {
            __syncthreads();
            constexpr int NWORD = CIB * K * Wp * 16;
            for (int i = tid; i < NWORD; i += 256) {
                int t16 = i & 15;
                int xi  = (i >> 4) % Wp;
                int ky  = ((i >> 4) / Wp) % K;
                int cl  = (i >> 4) / (Wp * K);
                int ci  = cb * CIB + cl;
                int row = h - P + ky;
                int xs  = xi - P;
                uint32_t v = 0;
                if ((unsigned)row < (unsigned)Hi && (unsigned)xs < (unsigned)Wi)
                    v = *(const uint32_t*)(sprev + in_b +
                          (((size_t)ci * Hi + row) * Wi + xs) * TPAD + tc * 64 + t16 * 4);
                ((uint32_t*)in_lds)[i] = v;
            }
            __syncthreads();

            #pragma unroll
            for (int cl = 0; cl < CIB; ++cl) {
                const int ci = cb * CIB + cl;
                #pragma unroll
                for (int ky = 0; ky < K; ++ky) {
                    #pragma unroll
                    for (int g = 0; g < WoS / WUN; ++g) {
                        float f[K + WUN - 1][4];
                        #pragma unroll
                        for (int j = 0; j < K + WUN - 1; ++j) {
                            uint32_t u = in_lds[cl][ky][wbase + g * WUN + j][tl];
                            f[j][0] = bcvt(u, 0); f[j][1] = bcvt(u, 1);
                            f[j][2] = bcvt(u, 2); f[j][3] = bcvt(u, 3);
                        }
                        #pragma unroll
                        for (int c = 0; c < CPS; ++c) {
                            const int coL = slot * CPS + c;
                            #pragma unroll
                            for (int kx = 0; kx < K; ++kx) {
                                const double wv = (double)w_lds[coL][(ci * K + ky) * K + kx];
                                #pragma unroll
                                for (int wu = 0; wu < WUN; ++wu)
                                    #pragma unroll
                                    for (int q = 0; q < 4; ++q)
                                        acc[c][g * WUN + wu][q] =
                                            fma(wv, (double)f[wu + kx][q], acc[c][g * WUN + wu][q]);
                            }
                        }
                    }
                }
            }
        }

        #pragma unroll
        for (int c = 0; c < CPS; ++c) {
            const int coL = slot * CPS + c;
            #pragma unroll
            for (int w = 0; w < WoS; ++w) {
                size_t off = ((((size_t)b * Co_total + co0 + coL) * Ho + h) * Wo + wbase + w)
                             * TPAD + tc * 64 + tl * 4;
                *(double2*)(z + off)     = make_double2(acc[c][w][0], acc[c][w][1]);
                *(double2*)(z + off + 2) = make_double2(acc[c][w][2], acc[c][w][3]);
            }
        }
    }
}

// ---------------------------------------------------------------------------
// Pool: z = 11.000000000000002 * (2x2 spike count), f64 (== np serial sum).
// ---------------------------------------------------------------------------
template<int C, int Hi>
__global__ __launch_bounds__(256) void pool_z_kernel(
    const uint8_t* __restrict__ sprev, double* __restrict__ z, int N)
{
    constexpr int Wi = Hi, Ho = Hi / 2, Wo = Wi / 2;
    int n = blockIdx.x * 256 + threadIdx.x;
    if (n >= N) return;
    int wo = n % Wo;  int r1 = n / Wo;
    int ho = r1 % Ho; int r2 = r1 / Ho;
    int c  = r2 % C;  int b  = r2 / C;
    const uint8_t* p0 = sprev + ((((size_t)b * C + c) * Hi + 2 * ho) * Wi + 2 * wo) * TPAD;
    const uint8_t* p1 = p0 + TPAD;
    const uint8_t* p2 = p0 + (size_t)Wi * TPAD;
    const uint8_t* p3 = p2 + TPAD;
    double* zr = z + (size_t)n * TPAD;
    for (int t0 = 0; t0 < TPAD; t0 += 4) {
        uint32_t a0 = *(const uint32_t*)(p0 + t0), a1 = *(const uint32_t*)(p1 + t0);
        uint32_t a2 = *(const uint32_t*)(p2 + t0), a3 = *(const uint32_t*)(p3 + t0);
        #pragma unroll
        for (int j = 0; j < 4; ++j) {
            int sh = 8 * j;
            int cnt = (int)(((a0 >> sh) & 255u) + ((a1 >> sh) & 255u) +
                            ((a2 >> sh) & 255u) + ((a3 >> sh) & 255u));
            zr[t0 + j] = POOL_W * (double)cnt;
        }
    }
}

// ---------------------------------------------------------------------------
// Fused PSP(FIR, f64) + refractory spike scan (f64). Block = one neuron row.
// FIR t-parallel into LDS; lane 0 does the serial 300-step scan.
// ---------------------------------------------------------------------------
__global__ __launch_bounds__(320) void psp_spike_kernel(
    const double* __restrict__ z, const double* __restrict__ epsd,
    uint8_t* __restrict__ sout)
{
    __shared__ double zb[TPAD];
    __shared__ double ab[TREAL];
    __shared__ double ef[100];
    __shared__ uint8_t sb[TPAD];
    const int row = blockIdx.x;
    const int t = threadIdx.x;
    if (t < 100) ef[t] = epsd[t];
    zb[t] = z[(size_t)row * TPAD + t];
    __syncthreads();
    if (t < TREAL) {
        double acc = 0.0;
        const int km = (t < 99) ? t : 99;
        for (int k = 1; k <= km; ++k)
            acc = fma(ef[k], zb[t - k], acc);
        ab[t] = acc;
    }
    __syncthreads();
    if (t == 0) {
        double r = 0.0;
        #pragma unroll 4
        for (int i = 0; i < TREAL; ++i) {
            double u = ab[i] + r;
            bool s = (u >= 10.0);
            r = REF_DEC * (r - (s ? 20.0 : 0.0));
            sb[i] = s ? 1 : 0;
        }
    }
    if (t >= TREAL) sb[t] = 0;
    __syncthreads();
    if (t < 80) {
        uint32_t w = (uint32_t)sb[t * 4] | ((uint32_t)sb[t * 4 + 1] << 8) |
                     ((uint32_t)sb[t * 4 + 2] << 16) | ((uint32_t)sb[t * 4 + 3] << 24);
        *(uint32_t*)(sout + (size_t)row * TPAD + t * 4) = w;
    }
}

// ---------------------------------------------------------------------------
// Dense: f64 accumulation (exact, order-free) -> z6 f64.  Grid (5, Bg).
// ---------------------------------------------------------------------------
__global__ __launch_bounds__(256) void dense_kernel(
    const uint8_t* __restrict__ s5, const float* __restrict__ Wf,
    double* __restrict__ z6)
{
    const int tc = blockIdx.x, b = blockIdx.y;
    const int tid = threadIdx.x;
    const int tl = tid & 63, slot = tid >> 6;
    const int t = tc * 64 + tl;
    double acc[10];
    #pragma unroll
    for (int o = 0; o < 10; ++o) acc[o] = 0.0;
    const uint8_t* sp = s5 + (size_t)b * 4096 * TPAD + t;
    for (int i = slot * 1024; i < (slot + 1) * 1024; ++i) {
        float f = (float)sp[(size_t)i * TPAD];
        if (__any(f != 0.f)) {   // skipping exact-zero adds preserves the exact sum
            #pragma unroll
            for (int o = 0; o < 10; ++o)
                acc[o] = fma((double)Wf[o * 4096 + i], (double)f, acc[o]);
        }
    }
    __shared__ double red[4][64][10];
    #pragma unroll
    for (int o = 0; o < 10; ++o) red[slot][tl][o] = acc[o];
    __syncthreads();
    if (slot == 0) {
        #pragma unroll
        for (int o = 0; o < 10; ++o) {
            double v = (red[0][tl][o] + red[1][tl][o]) + (red[2][tl][o] + red[3][tl][o]);
            z6[((size_t)b * 10 + o) * TPAD + t] = v;
        }
    }
}

// ---------------------------------------------------------------------------
// Final u8 spikes -> d_out (bf16 {0,1}, or f32 fallback), dropping TPAD pad.
// ---------------------------------------------------------------------------
__global__ __launch_bounds__(256) void out_kernel(
    const uint8_t* __restrict__ s6, void* __restrict__ out, size_t obase, int n,
    const int* __restrict__ flag)
{
    int idx = blockIdx.x * 256 + threadIdx.x;
    if (idx >= n) return;
    int row = idx / TREAL, t = idx - row * TREAL;
    uint8_t s = s6[(size_t)row * TPAD + t];
    if (*flag) ((uint16_t*)out)[obase + idx] = s ? 0x3F80 : 0;
    else       ((float*)out)[obase + idx] = s ? 1.0f : 0.0f;
}

// ---------------------------------------------------------------------------
__global__ __launch_bounds__(256) void fill_kernel(float* __restrict__ out, int n, float v)
{
    int i = blockIdx.x * 256 + threadIdx.x;
    if (i < n) out[i] = v;
}

// ---------------------------------------------------------------------------
static inline size_t alignup(size_t x) { return (x + 255) & ~(size_t)255; }

extern "C" void kernel_launch(void* const* d_in, const int* in_sizes, int n_in,
                              void* d_out, int out_size, void* d_ws, size_t ws_size,
                              hipStream_t stream)
{
    if (n_in != 5 || in_sizes[0] != 16 * 2 * 34 * 34 * 300 || in_sizes[1] != 800 ||
        in_sizes[2] != 4608 || in_sizes[3] != 18432 || in_sizes[4] != 40960 ||
        out_size != 16 * 10 * 300) {
        fill_kernel<<<(out_size + 255) / 256, 256, 0, stream>>>((float*)d_out, out_size, 2.0e5f);
        return;
    }

    const int NW[4] = {800, 4608, 18432, 40960};
    const size_t flag_sz = alignup(sizeof(int));
    const size_t eps_sz  = alignup(100 * sizeof(double));
    const size_t wf32_sz = alignup((size_t)(800 + 4608 + 18432 + 40960) * 4);
    const size_t sin8_sz = alignup((size_t)16 * 2 * 34 * 34 * TPAD);

    int G = -1;
    const int cand[5] = {1, 2, 4, 8, 16};
    for (int k = 0; k < 5; ++k) {
        int g = cand[k];
        int bg = 16 / g;
        size_t need = flag_sz + eps_sz + wf32_sz + sin8_sz
            + alignup((size_t)bg * 16384 * TPAD * 8)   // z slot (f64, max layer = L1)
            + alignup((size_t)bg * 16384 * TPAD)       // spikes A
            + alignup((size_t)bg * 4096 * TPAD)        // spikes B
            + alignup((size_t)bg * 10 * TPAD * 8)      // z6 (f64)
            + alignup((size_t)bg * 10 * TPAD);         // s6
        if (need <= ws_size) { G = g; break; }
    }
    if (G < 0) {
        fill_kernel<<<(out_size + 255) / 256, 256, 0, stream>>>((float*)d_out, out_size, 1.0e5f);
        return;
    }
    const int Bg = 16 / G;

    char* base = (char*)d_ws;
    int* flag = (int*)base;          base += flag_sz;
    double* epsd = (double*)base;    base += eps_sz;
    float* wf32 = (float*)base;      base += wf32_sz;
    uint8_t* sin8 = (uint8_t*)base;  base += sin8_sz;
    double* z64 = (double*)base;     base += alignup((size_t)Bg * 16384 * TPAD * 8);
    uint8_t* sA = (uint8_t*)base;    base += alignup((size_t)Bg * 16384 * TPAD);
    uint8_t* sB = (uint8_t*)base;    base += alignup((size_t)Bg * 4096 * TPAD);
    double* z6b = (double*)base;     base += alignup((size_t)Bg * 10 * TPAD * 8);
    uint8_t* s6b = (uint8_t*)base;

    detect_kernel<<<1, 64, 0, stream>>>((const uint16_t*)d_in[1], flag);
    eps_kernel<<<1, 128, 0, stream>>>(epsd);
    float* Wf32[4];
    {
        size_t off = 0;
        for (int i = 0; i < 4; ++i) {
            Wf32[i] = wf32 + off;
            wcvt_kernel<<<(NW[i] + 255) / 256, 256, 0, stream>>>(d_in[1 + i], Wf32[i], NW[i], flag);
            off += NW[i];
        }
    }
    convert_kernel<<<16 * 2 * 34 * 34, 320, 0, stream>>>(d_in[0], sin8, flag);

    for (int g = 0; g < G; ++g) {
        const int b0 = g * Bg;
        const int N1 = Bg * 16 * 32 * 32;
        const int N2 = Bg * 16 * 16 * 16;
        const int N3 = Bg * 32 * 16 * 16;
        const int N4 = Bg * 32 * 8 * 8;
        const int N5 = Bg * 64 * 8 * 8;
        const int N6 = Bg * 10;

        // L1: conv 2->16, 5x5 pad1, 34->32
        conv_kernel<2, 2, 16, 5, 34, 34, 1, 4, 4><<<dim3(32, 4, Bg), 256, 0, stream>>>(
            sin8 + (size_t)b0 * 2 * 34 * 34 * TPAD, Wf32[0], z64, 16);
        psp_spike_kernel<<<N1, 320, 0, stream>>>(z64, epsd, sA);

        // L2: pool 32->16
        pool_z_kernel<16, 32><<<(N2 + 255) / 256, 256, 0, stream>>>(sA, z64, N2);
        psp_spike_kernel<<<N2, 320, 0, stream>>>(z64, epsd, sB);

        // L3: conv 16->32, 3x3 pad1, 16->16
        conv_kernel<16, 8, 32, 3, 16, 16, 2, 4, 4><<<dim3(16, 4, Bg), 256, 0, stream>>>(
            sB, Wf32[1], z64, 32);
        psp_spike_kernel<<<N3, 320, 0, stream>>>(z64, epsd, sA);

        // L4: pool 16->8
        pool_z_kernel<32, 16><<<(N4 + 255) / 256, 256, 0, stream>>>(sA, z64, N4);
        psp_spike_kernel<<<N4, 320, 0, stream>>>(z64, epsd, sB);

        // L5: conv 32->64, 3x3 pad1, 8->8
        conv_kernel<32, 8, 32, 3, 8, 8, 2, 4, 2><<<dim3(8, 4, Bg), 256, 0, stream>>>(
            sB, Wf32[2], z64, 64);
        psp_spike_kernel<<<N5, 320, 0, stream>>>(z64, epsd, sA);

        // L6: dense 4096->10 + final psp/spike -> d_out
        dense_kernel<<<dim3(5, Bg), 256, 0, stream>>>(sA, Wf32[3], z6b);
        psp_spike_kernel<<<N6, 320, 0, stream>>>(z6b, epsd, s6b);
        out_kernel<<<(N6 * TREAL + 255) / 256, 256, 0, stream>>>(
            s6b, d_out, (size_t)b0 * 10 * TREAL, N6 * TREAL, flag);
    }
}

// Round 8
// 4529.639 us; speedup vs baseline: 2.5799x; 2.5799x over previous
//
#include <hip/hip_runtime.h>
#include <hip/hip_bf16.h>
#include <stdint.h>
#include <stddef.h>

#define TPAD 320   // padded time stride (300 real + 20 pad)
#define TREAL 300

// Python-f64 pool weight: float(1.1*10.0)  (validated exact in round 7)
#define POOL_W   11.000000000000002

static __device__ __forceinline__ float bf2f(uint16_t b) {
    return __uint_as_float(((uint32_t)b) << 16);
}
static __device__ __forceinline__ float bcvt(uint32_t u, int j) {
    return (float)((u >> (8 * j)) & 0xffu);
}

// ---------------------------------------------------------------------------
// f64 truncated-alpha IIR + refractory scan state.
// a[t] = C1*Q[t] - C2*Q2[t] - C3*P2[t];  (P,Q) filter z[t], (P2,Q2) filter
// z[t-100].  Impulse-verified: reproduces the 100-tap FIR to ~1e-13.
// Constants computed in f64 on device (<=1 ulp vs np, harmless at margins).
// ---------------------------------------------------------------------------
struct IIRC { double DD, C1, C2, C3, DR; };
static __device__ __forceinline__ IIRC iirc_make() {
    IIRC c;
    c.DD = exp(-0.1);
    c.C1 = exp(1.0) / 10.0;
    c.C2 = exp(-9.0) / 10.0;
    c.C3 = 10.0 * exp(-9.0);
    c.DR = exp(-1.0);           // np.exp(-1) = 0.36787944117144233
    return c;
}
struct IIRS { double P, Q, P2, Q2, r; };
static __device__ __forceinline__ void iirs_init(IIRS& s) {
    s.P = 0.0; s.Q = 0.0; s.P2 = 0.0; s.Q2 = 0.0; s.r = 0.0;
}
static __device__ __forceinline__ bool iir_step(const IIRC& c, IIRS& st,
                                                double x, double xd) {
    double Qn  = c.DD * (st.Q + st.P);
    double Pn  = fma(c.DD, st.P, x);
    double Q2n = c.DD * (st.Q2 + st.P2);
    double P2n = fma(c.DD, st.P2, xd);
    double a = c.C1 * Qn - c.C2 * Q2n - c.C3 * P2n;
    double u = a + st.r;
    bool s = (u >= 10.0);
    st.r = c.DR * (st.r - (s ? 20.0 : 0.0));
    st.P = Pn; st.Q = Qn; st.P2 = P2n; st.Q2 = Q2n;
    return s;
}

// ---------------------------------------------------------------------------
// Dtype detection (bf16 confirmed on HW in round 5; f32 fallback kept)
// ---------------------------------------------------------------------------
__global__ void detect_kernel(const uint16_t* __restrict__ w1raw, int* __restrict__ flag)
{
    if (threadIdx.x == 0 && blockIdx.x == 0) {
        int sane = 1;
        for (int i = 0; i < 800; ++i) {
            int e = (w1raw[i] >> 7) & 0xFF;
            if (e >= 131) { sane = 0; break; }
        }
        *flag = sane;   // 1 = bf16, 0 = f32
    }
}

// ---------------------------------------------------------------------------
// Weight convert -> f32 ws copy (bf16->f32 exact)
// ---------------------------------------------------------------------------
__global__ __launch_bounds__(256) void wcvt_kernel(
    const void* __restrict__ w, float* __restrict__ out, int n, const int* __restrict__ flag)
{
    int i = blockIdx.x * 256 + threadIdx.x;
    if (i >= n) return;
    out[i] = (*flag) ? bf2f(((const uint16_t*)w)[i]) : ((const float*)w)[i];
}

// ---------------------------------------------------------------------------
// Input (binary 0/1) -> uint8 spikes in TPAD layout (pad zeroed)
// ---------------------------------------------------------------------------
__global__ __launch_bounds__(320) void convert_kernel(
    const void* __restrict__ s_in, uint8_t* __restrict__ u8, const int* __restrict__ flag)
{
    int row = blockIdx.x;
    int t = threadIdx.x;
    uint8_t v = 0;
    if (t < TREAL) {
        float x = (*flag) ? bf2f(((const uint16_t*)s_in)[(size_t)row * TREAL + t])
                          : ((const float*)s_in)[(size_t)row * TREAL + t];
        v = (x >= 0.5f) ? 1 : 0;
    }
    u8[(size_t)row * TPAD + t] = v;
}

// ---------------------------------------------------------------------------
// Spatial conv, f64 accumulation (exact). tc moved into grid.z for 5x more
// blocks per launch.  Grid: (Ho, NWSPLIT * Co_total/CoB, Bg*5)
// ---------------------------------------------------------------------------
template<int Ci, int CIB, int CoB, int K, int Hi, int Wi, int CPS, int WUN, int NWSPLIT>
__global__ __launch_bounds__(256) void conv_kernel(
    const uint8_t* __restrict__ sprev,  // [Bg][Ci][Hi][Wi][TPAD]
    const float* __restrict__ Wg,       // [Co_total][Ci][K][K] (f32 = exact bf16)
    double* __restrict__ z,             // [Bg][Co_total][Ho][Wo][TPAD]
    int Co_total)
{
    static_assert(CoB == 16 * CPS, "slot layout");
    constexpr int P = 1;
    constexpr int Ho = Hi + 2 * P - K + 1;
    constexpr int Wo = Wi + 2 * P - K + 1;
    constexpr int Wp = Wi + 2 * P;
    constexpr int CKK = Ci * K * K;
    constexpr int WoS = Wo / NWSPLIT;
    constexpr int NCB = Ci / CIB;
    static_assert(Wo % NWSPLIT == 0 && WoS % WUN == 0 && Ci % CIB == 0, "split");

    __shared__ uint32_t in_lds[CIB][K][Wp][16];
    __shared__ float w_lds[CoB][CKK + 1];
    static_assert(sizeof(in_lds) + sizeof(w_lds) <= 60 * 1024, "LDS over limit");

    const int tid = threadIdx.x;
    const int h   = blockIdx.x;
    const int wsp = (int)blockIdx.y % NWSPLIT;
    const int co0 = ((int)blockIdx.y / NWSPLIT) * CoB;
    const int b   = (int)blockIdx.z / 5;
    const int tc  = (int)blockIdx.z % 5;
    const int wbase = wsp * WoS;

    for (int i = tid; i < CoB * CKK; i += 256) {
        int co = i / CKK, rest = i - co * CKK;
        w_lds[co][rest] = Wg[(size_t)(co0 + co) * CKK + rest];
    }

    const int slot = tid >> 4;
    const int tl   = tid & 15;
    const size_t in_b = (size_t)b * Ci * Hi * Wi * TPAD;

    double acc[CPS][WoS][4];
    #pragma unroll
    for (int c = 0; c < CPS; ++c)
        #pragma unroll
        for (int w = 0; w < WoS; ++w)
            #pragma unroll
            for (int q = 0; q < 4; ++q) acc[c][w][q] = 0.0;

    for (int cb = 0; cb < NCB; ++cb) {
        __syncthreads();   // covers w_lds stage (cb=0) and prior readers
        constexpr int NWORD = CIB * K * Wp * 16;
        for (int i = tid; i < NWORD; i += 256) {
            int t16 = i & 15;
            int xi  = (i >> 4) % Wp;
            int ky  = ((i >> 4) / Wp) % K;
            int cl  = (i >> 4) / (Wp * K);
            int ci  = cb * CIB + cl;
            int row = h - P + ky;
            int xs  = xi - P;
            uint32_t v = 0;
            if ((unsigned)row < (unsigned)Hi && (unsigned)xs < (unsigned)Wi)
                v = *(const uint32_t*)(sprev + in_b +
                      (((size_t)ci * Hi + row) * Wi + xs) * TPAD + tc * 64 + t16 * 4);
            ((uint32_t*)in_lds)[i] = v;
        }
        __syncthreads();

        #pragma unroll
        for (int cl = 0; cl < CIB; ++cl) {
            const int ci = cb * CIB + cl;
            #pragma unroll
            for (int ky = 0; ky < K; ++ky) {
                #pragma unroll
                for (int g = 0; g < WoS / WUN; ++g) {
                    float f[K + WUN - 1][4];
                    #pragma unroll
                    for (int j = 0; j < K + WUN - 1; ++j) {
                        uint32_t u = in_lds[cl][ky][wbase + g * WUN + j][tl];
                        f[j][0] = bcvt(u, 0); f[j][1] = bcvt(u, 1);
                        f[j][2] = bcvt(u, 2); f[j][3] = bcvt(u, 3);
                    }
                    #pragma unroll
                    for (int c = 0; c < CPS; ++c) {
                        const int coL = slot * CPS + c;
                        #pragma unroll
                        for (int kx = 0; kx < K; ++kx) {
                            const double wv = (double)w_lds[coL][(ci * K + ky) * K + kx];
                            #pragma unroll
                            for (int wu = 0; wu < WUN; ++wu)
                                #pragma unroll
                                for (int q = 0; q < 4; ++q)
                                    acc[c][g * WUN + wu][q] =
                                        fma(wv, (double)f[wu + kx][q], acc[c][g * WUN + wu][q]);
                        }
                    }
                }
            }
        }
    }

    #pragma unroll
    for (int c = 0; c < CPS; ++c) {
        const int coL = slot * CPS + c;
        #pragma unroll
        for (int w = 0; w < WoS; ++w) {
            size_t off = ((((size_t)b * Co_total + co0 + coL) * Ho + h) * Wo + wbase + w)
                         * TPAD + tc * 64 + tl * 4;
            *(double2*)(z + off)     = make_double2(acc[c][w][0], acc[c][w][1]);
            *(double2*)(z + off + 2) = make_double2(acc[c][w][2], acc[c][w][3]);
        }
    }
}

// ---------------------------------------------------------------------------
// IIR-PSP + spike scan over stored f64 z.  Lane = neuron row (fully parallel
// across rows; serial over t only).  Replaces FIR+serial-lane-0 scan.
// ---------------------------------------------------------------------------
__global__ __launch_bounds__(256) void psp_iir_kernel(
    const double* __restrict__ z, uint8_t* __restrict__ sout, int N)
{
    int n = blockIdx.x * 256 + threadIdx.x;
    if (n >= N) return;
    const double* zr = z + (size_t)n * TPAD;
    uint8_t* sr = sout + (size_t)n * TPAD;
    const IIRC c = iirc_make();
    IIRS st; iirs_init(st);
    for (int t0 = 0; t0 < TREAL; t0 += 4) {
        uint32_t sw = 0;
        #pragma unroll
        for (int j = 0; j < 4; ++j) {
            int t = t0 + j;
            double x = zr[t];
            double xd = (t0 >= 100) ? zr[t - 100] : 0.0;   // t0>=100 <=> t>=100 (t0%4==0)
            if (iir_step(c, st, x, xd)) sw |= 1u << (8 * j);
        }
        *(uint32_t*)(sr + t0) = sw;
    }
    #pragma unroll
    for (int t0 = TREAL; t0 < TPAD; t0 += 4) *(uint32_t*)(sr + t0) = 0;
}

// ---------------------------------------------------------------------------
// Fused pool(2x2, w=POOL_W) + IIR-PSP + scan.  Delayed input recomputed from
// spikes at t-100 (no z materialization at all for pool layers).
// ---------------------------------------------------------------------------
template<int C, int Hi>
__global__ __launch_bounds__(256) void pool_psp_iir_kernel(
    const uint8_t* __restrict__ sprev, uint8_t* __restrict__ sout, int N)
{
    constexpr int Wi = Hi, Ho = Hi / 2, Wo = Wi / 2;
    int n = blockIdx.x * 256 + threadIdx.x;
    if (n >= N) return;
    int wo = n % Wo;  int r1 = n / Wo;
    int ho = r1 % Ho; int r2 = r1 / Ho;
    int cc = r2 % C;  int b  = r2 / C;
    const uint8_t* p0 = sprev + ((((size_t)b * C + cc) * Hi + 2 * ho) * Wi + 2 * wo) * TPAD;
    const uint8_t* p1 = p0 + TPAD;
    const uint8_t* p2 = p0 + (size_t)Wi * TPAD;
    const uint8_t* p3 = p2 + TPAD;
    uint8_t* sr = sout + (size_t)n * TPAD;
    const IIRC c = iirc_make();
    IIRS st; iirs_init(st);
    for (int t0 = 0; t0 < TREAL; t0 += 4) {
        uint32_t a0 = *(const uint32_t*)(p0 + t0), a1 = *(const uint32_t*)(p1 + t0);
        uint32_t a2 = *(const uint32_t*)(p2 + t0), a3 = *(const uint32_t*)(p3 + t0);
        uint32_t d0 = 0, d1 = 0, d2 = 0, d3 = 0;
        if (t0 >= 100) {
            d0 = *(const uint32_t*)(p0 + t0 - 100); d1 = *(const uint32_t*)(p1 + t0 - 100);
            d2 = *(const uint32_t*)(p2 + t0 - 100); d3 = *(const uint32_t*)(p3 + t0 - 100);
        }
        uint32_t sw = 0;
        #pragma unroll
        for (int j = 0; j < 4; ++j) {
            int sh = 8 * j;
            int cnt  = (int)(((a0 >> sh) & 255u) + ((a1 >> sh) & 255u) +
                             ((a2 >> sh) & 255u) + ((a3 >> sh) & 255u));
            int cntd = (int)(((d0 >> sh) & 255u) + ((d1 >> sh) & 255u) +
                             ((d2 >> sh) & 255u) + ((d3 >> sh) & 255u));
            double x  = POOL_W * (double)cnt;
            double xd = POOL_W * (double)cntd;
            if (iir_step(c, st, x, xd)) sw |= 1u << sh;
        }
        *(uint32_t*)(sr + t0) = sw;
    }
    #pragma unroll
    for (int t0 = TREAL; t0 < TPAD; t0 += 4) *(uint32_t*)(sr + t0) = 0;
}

// ---------------------------------------------------------------------------
// Dense partials: grid (5, Bg, 16).  Each block reduces a 256-chw slice for
// 64 t's into partial[p][b][o][t] (f64).  16x more blocks than round 7.
// ---------------------------------------------------------------------------
__global__ __launch_bounds__(256) void dense_partial_kernel(
    const uint8_t* __restrict__ s5, const float* __restrict__ Wf,
    double* __restrict__ partial, int Bg)
{
    const int tc = blockIdx.x, b = blockIdx.y, p = blockIdx.z;
    const int tid = threadIdx.x;
    const int tl = tid & 63, slot = tid >> 6;
    const int t = tc * 64 + tl;
    const int i0 = p * 256 + slot * 64;
    double acc[10];
    #pragma unroll
    for (int o = 0; o < 10; ++o) acc[o] = 0.0;
    const uint8_t* sp = s5 + ((size_t)b * 4096 + i0) * TPAD + t;
    for (int i = 0; i < 64; ++i) {
        float f = (float)sp[(size_t)i * TPAD];
        if (__any(f != 0.f)) {   // skipping exact-zero adds preserves the exact sum
            #pragma unroll
            for (int o = 0; o < 10; ++o)
                acc[o] = fma((double)Wf[o * 4096 + i0 + i], (double)f, acc[o]);
        }
    }
    __shared__ double red[4][64][10];
    #pragma unroll
    for (int o = 0; o < 10; ++o) red[slot][tl][o] = acc[o];
    __syncthreads();
    if (slot == 0) {
        #pragma unroll
        for (int o = 0; o < 10; ++o) {
            double v = ((red[0][tl][o] + red[1][tl][o]) + red[2][tl][o]) + red[3][tl][o];
            partial[(((size_t)p * Bg + b) * 10 + o) * TPAD + t] = v;
        }
    }
}

// ---------------------------------------------------------------------------
// Final: sum 16 dense partials (fixed ascending order), IIR-PSP + scan,
// write d_out directly (bf16 {0,1} or f32 fallback).  Lane = (b,o) row.
// ---------------------------------------------------------------------------
__global__ __launch_bounds__(256) void psp_out_kernel(
    const double* __restrict__ partial, void* __restrict__ out, size_t obase,
    int NR, int Bg, const int* __restrict__ flag)
{
    int n = blockIdx.x * 256 + threadIdx.x;
    if (n >= NR) return;
    int b = n / 10, o = n % 10;
    const bool isbf = (*flag != 0);
    const IIRC c = iirc_make();
    IIRS st; iirs_init(st);
    for (int t = 0; t < TREAL; ++t) {
        double x = 0.0, xd = 0.0;
        #pragma unroll
        for (int p = 0; p < 16; ++p)
            x += partial[(((size_t)p * Bg + b) * 10 + o) * TPAD + t];
        if (t >= 100) {
            #pragma unroll
            for (int p = 0; p < 16; ++p)
                xd += partial[(((size_t)p * Bg + b) * 10 + o) * TPAD + (t - 100)];
        }
        bool s = iir_step(c, st, x, xd);
        size_t e = obase + (size_t)n * TREAL + t;
        if (isbf) ((uint16_t*)out)[e] = s ? 0x3F80 : 0;
        else      ((float*)out)[e] = s ? 1.0f : 0.0f;
    }
}

// ---------------------------------------------------------------------------
__global__ __launch_bounds__(256) void fill_kernel(float* __restrict__ out, int n, float v)
{
    int i = blockIdx.x * 256 + threadIdx.x;
    if (i < n) out[i] = v;
}

// ---------------------------------------------------------------------------
static inline size_t alignup(size_t x) { return (x + 255) & ~(size_t)255; }

extern "C" void kernel_launch(void* const* d_in, const int* in_sizes, int n_in,
                              void* d_out, int out_size, void* d_ws, size_t ws_size,
                              hipStream_t stream)
{
    if (n_in != 5 || in_sizes[0] != 16 * 2 * 34 * 34 * 300 || in_sizes[1] != 800 ||
        in_sizes[2] != 4608 || in_sizes[3] != 18432 || in_sizes[4] != 40960 ||
        out_size != 16 * 10 * 300) {
        fill_kernel<<<(out_size + 255) / 256, 256, 0, stream>>>((float*)d_out, out_size, 2.0e5f);
        return;
    }

    const int NW[4] = {800, 4608, 18432, 40960};
    const size_t flag_sz = alignup(sizeof(int));
    const size_t wf32_sz = alignup((size_t)(800 + 4608 + 18432 + 40960) * 4);
    const size_t sin8_sz = alignup((size_t)16 * 2 * 34 * 34 * TPAD);

    int G = -1;
    const int cand[5] = {1, 2, 4, 8, 16};
    for (int k = 0; k < 5; ++k) {
        int g = cand[k];
        int bg = 16 / g;
        size_t need = flag_sz + wf32_sz + sin8_sz
            + alignup((size_t)bg * 16384 * TPAD * 8)        // z (f64, max = L1)
            + alignup((size_t)bg * 16384 * TPAD)            // spikes A
            + alignup((size_t)bg * 4096 * TPAD)             // spikes B
            + alignup((size_t)16 * bg * 10 * TPAD * 8);     // dense partials
        if (need <= ws_size) { G = g; break; }
    }
    if (G < 0) {
        fill_kernel<<<(out_size + 255) / 256, 256, 0, stream>>>((float*)d_out, out_size, 1.0e5f);
        return;
    }
    const int Bg = 16 / G;

    char* base = (char*)d_ws;
    int* flag = (int*)base;          base += flag_sz;
    float* wf32 = (float*)base;      base += wf32_sz;
    uint8_t* sin8 = (uint8_t*)base;  base += sin8_sz;
    double* z64 = (double*)base;     base += alignup((size_t)Bg * 16384 * TPAD * 8);
    uint8_t* sA = (uint8_t*)base;    base += alignup((size_t)Bg * 16384 * TPAD);
    uint8_t* sB = (uint8_t*)base;    base += alignup((size_t)Bg * 4096 * TPAD);
    double* dpart = (double*)base;

    detect_kernel<<<1, 64, 0, stream>>>((const uint16_t*)d_in[1], flag);
    float* Wf32[4];
    {
        size_t off = 0;
        for (int i = 0; i < 4; ++i) {
            Wf32[i] = wf32 + off;
            wcvt_kernel<<<(NW[i] + 255) / 256, 256, 0, stream>>>(d_in[1 + i], Wf32[i], NW[i], flag);
            off += NW[i];
        }
    }
    convert_kernel<<<16 * 2 * 34 * 34, 320, 0, stream>>>(d_in[0], sin8, flag);

    for (int g = 0; g < G; ++g) {
        const int b0 = g * Bg;
        const int N1 = Bg * 16 * 32 * 32;
        const int N2 = Bg * 16 * 16 * 16;
        const int N3 = Bg * 32 * 16 * 16;
        const int N4 = Bg * 32 * 8 * 8;
        const int N5 = Bg * 64 * 8 * 8;
        const int N6 = Bg * 10;

        // L1: conv 2->16, 5x5 pad1, 34->32
        conv_kernel<2, 2, 16, 5, 34, 34, 1, 4, 4><<<dim3(32, 4, Bg * 5), 256, 0, stream>>>(
            sin8 + (size_t)b0 * 2 * 34 * 34 * TPAD, Wf32[0], z64, 16);
        psp_iir_kernel<<<(N1 + 255) / 256, 256, 0, stream>>>(z64, sA, N1);

        // L2: fused pool+psp 32->16
        pool_psp_iir_kernel<16, 32><<<(N2 + 255) / 256, 256, 0, stream>>>(sA, sB, N2);

        // L3: conv 16->32, 3x3 pad1, 16->16
        conv_kernel<16, 8, 32, 3, 16, 16, 2, 4, 4><<<dim3(16, 4, Bg * 5), 256, 0, stream>>>(
            sB, Wf32[1], z64, 32);
        psp_iir_kernel<<<(N3 + 255) / 256, 256, 0, stream>>>(z64, sA, N3);

        // L4: fused pool+psp 16->8
        pool_psp_iir_kernel<32, 16><<<(N4 + 255) / 256, 256, 0, stream>>>(sA, sB, N4);

        // L5: conv 32->64, 3x3 pad1, 8->8
        conv_kernel<32, 8, 32, 3, 8, 8, 2, 4, 2><<<dim3(8, 4, Bg * 5), 256, 0, stream>>>(
            sB, Wf32[2], z64, 64);
        psp_iir_kernel<<<(N5 + 255) / 256, 256, 0, stream>>>(z64, sA, N5);

        // L6: dense partials + final psp/out
        dense_partial_kernel<<<dim3(5, Bg, 16), 256, 0, stream>>>(sA, Wf32[3], dpart, Bg);
        psp_out_kernel<<<(N6 + 255) / 256, 256, 0, stream>>>(
            dpart, d_out, (size_t)b0 * 10 * TREAL, N6, Bg, flag);
    }
}

// Round 9
// 3607.475 us; speedup vs baseline: 3.2393x; 1.2556x over previous
//
#include <hip/hip_runtime.h>
#include <hip/hip_bf16.h>
#include <stdint.h>
#include <stddef.h>

#define TPAD 320   // padded time stride (300 real + 20 pad)
#define TREAL 300

// Python-f64 pool weight: float(1.1*10.0)  (validated exact in rounds 7/8)
#define POOL_W   11.000000000000002

static __device__ __forceinline__ float bf2f(uint16_t b) {
    return __uint_as_float(((uint32_t)b) << 16);
}
static __device__ __forceinline__ float bcvt(uint32_t u, int j) {
    return (float)((u >> (8 * j)) & 0xffu);
}

// ---------------------------------------------------------------------------
// f64 truncated-alpha IIR + refractory scan (validated exact in round 8).
// ---------------------------------------------------------------------------
struct IIRC { double DD, C1, C2, C3, DR; };
static __device__ __forceinline__ IIRC iirc_make() {
    IIRC c;
    c.DD = exp(-0.1);
    c.C1 = exp(1.0) / 10.0;
    c.C2 = exp(-9.0) / 10.0;
    c.C3 = 10.0 * exp(-9.0);
    c.DR = exp(-1.0);
    return c;
}
struct IIRS { double P, Q, P2, Q2, r; };
static __device__ __forceinline__ void iirs_init(IIRS& s) {
    s.P = 0.0; s.Q = 0.0; s.P2 = 0.0; s.Q2 = 0.0; s.r = 0.0;
}
static __device__ __forceinline__ bool iir_step(const IIRC& c, IIRS& st,
                                                double x, double xd) {
    double Qn  = c.DD * (st.Q + st.P);
    double Pn  = fma(c.DD, st.P, x);
    double Q2n = c.DD * (st.Q2 + st.P2);
    double P2n = fma(c.DD, st.P2, xd);
    double a = c.C1 * Qn - c.C2 * Q2n - c.C3 * P2n;
    double u = a + st.r;
    bool s = (u >= 10.0);
    st.r = c.DR * (st.r - (s ? 20.0 : 0.0));
    st.P = Pn; st.Q = Qn; st.P2 = P2n; st.Q2 = Q2n;
    return s;
}

// ---------------------------------------------------------------------------
__global__ void detect_kernel(const uint16_t* __restrict__ w1raw, int* __restrict__ flag)
{
    if (threadIdx.x == 0 && blockIdx.x == 0) {
        int sane = 1;
        for (int i = 0; i < 800; ++i) {
            int e = (w1raw[i] >> 7) & 0xFF;
            if (e >= 131) { sane = 0; break; }
        }
        *flag = sane;   // 1 = bf16, 0 = f32
    }
}

__global__ __launch_bounds__(256) void wcvt_kernel(
    const void* __restrict__ w, float* __restrict__ out, int n, const int* __restrict__ flag)
{
    int i = blockIdx.x * 256 + threadIdx.x;
    if (i >= n) return;
    out[i] = (*flag) ? bf2f(((const uint16_t*)w)[i]) : ((const float*)w)[i];
}

__global__ __launch_bounds__(320) void convert_kernel(
    const void* __restrict__ s_in, uint8_t* __restrict__ u8, const int* __restrict__ flag)
{
    int row = blockIdx.x;
    int t = threadIdx.x;
    uint8_t v = 0;
    if (t < TREAL) {
        float x = (*flag) ? bf2f(((const uint16_t*)s_in)[(size_t)row * TREAL + t])
                          : ((const float*)s_in)[(size_t)row * TREAL + t];
        v = (x >= 0.5f) ? 1 : 0;
    }
    u8[(size_t)row * TPAD + t] = v;
}

// ---------------------------------------------------------------------------
// Spatial conv, f64 accumulation (exact). Grid: (Ho, NWSPLIT*Co/CoB, Bg*5)
// ---------------------------------------------------------------------------
template<int Ci, int CIB, int CoB, int K, int Hi, int Wi, int CPS, int WUN, int NWSPLIT>
__global__ __launch_bounds__(256) void conv_kernel(
    const uint8_t* __restrict__ sprev,  // [Bg][Ci][Hi][Wi][TPAD]
    const float* __restrict__ Wg,       // [Co_total][Ci][K][K] (f32 = exact bf16)
    double* __restrict__ z,             // [Bg][Co_total][Ho][Wo][TPAD]
    int Co_total)
{
    static_assert(CoB == 16 * CPS, "slot layout");
    constexpr int P = 1;
    constexpr int Ho = Hi + 2 * P - K + 1;
    constexpr int Wo = Wi + 2 * P - K + 1;
    constexpr int Wp = Wi + 2 * P;
    constexpr int CKK = Ci * K * K;
    constexpr int WoS = Wo / NWSPLIT;
    constexpr int NCB = Ci / CIB;
    static_assert(Wo % NWSPLIT == 0 && WoS % WUN == 0 && Ci % CIB == 0, "split");

    __shared__ uint32_t in_lds[CIB][K][Wp][16];
    __shared__ float w_lds[CoB][CKK + 1];
    static_assert(sizeof(in_lds) + sizeof(w_lds) <= 60 * 1024, "LDS over limit");

    const int tid = threadIdx.x;
    const int h   = blockIdx.x;
    const int wsp = (int)blockIdx.y % NWSPLIT;
    const int co0 = ((int)blockIdx.y / NWSPLIT) * CoB;
    const int b   = (int)blockIdx.z / 5;
    const int tc  = (int)blockIdx.z % 5;
    const int wbase = wsp * WoS;

    for (int i = tid; i < CoB * CKK; i += 256) {
        int co = i / CKK, rest = i - co * CKK;
        w_lds[co][rest] = Wg[(size_t)(co0 + co) * CKK + rest];
    }

    const int slot = tid >> 4;
    const int tl   = tid & 15;
    const size_t in_b = (size_t)b * Ci * Hi * Wi * TPAD;

    double acc[CPS][WoS][4];
    #pragma unroll
    for (int c = 0; c < CPS; ++c)
        #pragma unroll
        for (int w = 0; w < WoS; ++w)
            #pragma unroll
            for (int q = 0; q < 4; ++q) acc[c][w][q] = 0.0;

    for (int cb = 0; cb < NCB; ++cb) {
        __syncthreads();
        constexpr int NWORD = CIB * K * Wp * 16;
        for (int i = tid; i < NWORD; i += 256) {
            int t16 = i & 15;
            int xi  = (i >> 4) % Wp;
            int ky  = ((i >> 4) / Wp) % K;
            int cl  = (i >> 4) / (Wp * K);
            int ci  = cb * CIB + cl;
            int row = h - P + ky;
            int xs  = xi - P;
            uint32_t v = 0;
            if ((unsigned)row < (unsigned)Hi && (unsigned)xs < (unsigned)Wi)
                v = *(const uint32_t*)(sprev + in_b +
                      (((size_t)ci * Hi + row) * Wi + xs) * TPAD + tc * 64 + t16 * 4);
            ((uint32_t*)in_lds)[i] = v;
        }
        __syncthreads();

        #pragma unroll
        for (int cl = 0; cl < CIB; ++cl) {
            const int ci = cb * CIB + cl;
            #pragma unroll
            for (int ky = 0; ky < K; ++ky) {
                #pragma unroll
                for (int g = 0; g < WoS / WUN; ++g) {
                    float f[K + WUN - 1][4];
                    #pragma unroll
                    for (int j = 0; j < K + WUN - 1; ++j) {
                        uint32_t u = in_lds[cl][ky][wbase + g * WUN + j][tl];
                        f[j][0] = bcvt(u, 0); f[j][1] = bcvt(u, 1);
                        f[j][2] = bcvt(u, 2); f[j][3] = bcvt(u, 3);
                    }
                    #pragma unroll
                    for (int c = 0; c < CPS; ++c) {
                        const int coL = slot * CPS + c;
                        #pragma unroll
                        for (int kx = 0; kx < K; ++kx) {
                            const double wv = (double)w_lds[coL][(ci * K + ky) * K + kx];
                            #pragma unroll
                            for (int wu = 0; wu < WUN; ++wu)
                                #pragma unroll
                                for (int q = 0; q < 4; ++q)
                                    acc[c][g * WUN + wu][q] =
                                        fma(wv, (double)f[wu + kx][q], acc[c][g * WUN + wu][q]);
                        }
                    }
                }
            }
        }
    }

    #pragma unroll
    for (int c = 0; c < CPS; ++c) {
        const int coL = slot * CPS + c;
        #pragma unroll
        for (int w = 0; w < WoS; ++w) {
            size_t off = ((((size_t)b * Co_total + co0 + coL) * Ho + h) * Wo + wbase + w)
                         * TPAD + tc * 64 + tl * 4;
            *(double2*)(z + off)     = make_double2(acc[c][w][0], acc[c][w][1]);
            *(double2*)(z + off + 2) = make_double2(acc[c][w][2], acc[c][w][3]);
        }
    }
}

// ---------------------------------------------------------------------------
// IIR-PSP + spike scan over stored f64 z.  Lane = neuron row.
// ---------------------------------------------------------------------------
__global__ __launch_bounds__(256) void psp_iir_kernel(
    const double* __restrict__ z, uint8_t* __restrict__ sout, int N)
{
    int n = blockIdx.x * 256 + threadIdx.x;
    if (n >= N) return;
    const double* zr = z + (size_t)n * TPAD;
    uint8_t* sr = sout + (size_t)n * TPAD;
    const IIRC c = iirc_make();
    IIRS st; iirs_init(st);
    for (int t0 = 0; t0 < TREAL; t0 += 4) {
        uint32_t sw = 0;
        #pragma unroll
        for (int j = 0; j < 4; ++j) {
            int t = t0 + j;
            double x = zr[t];
            double xd = (t0 >= 100) ? zr[t - 100] : 0.0;
            if (iir_step(c, st, x, xd)) sw |= 1u << (8 * j);
        }
        *(uint32_t*)(sr + t0) = sw;
    }
    #pragma unroll
    for (int t0 = TREAL; t0 < TPAD; t0 += 4) *(uint32_t*)(sr + t0) = 0;
}

// ---------------------------------------------------------------------------
// Fused pool(2x2, w=POOL_W) + IIR-PSP + scan.
// ---------------------------------------------------------------------------
template<int C, int Hi>
__global__ __launch_bounds__(256) void pool_psp_iir_kernel(
    const uint8_t* __restrict__ sprev, uint8_t* __restrict__ sout, int N)
{
    constexpr int Wi = Hi, Ho = Hi / 2, Wo = Wi / 2;
    int n = blockIdx.x * 256 + threadIdx.x;
    if (n >= N) return;
    int wo = n % Wo;  int r1 = n / Wo;
    int ho = r1 % Ho; int r2 = r1 / Ho;
    int cc = r2 % C;  int b  = r2 / C;
    const uint8_t* p0 = sprev + ((((size_t)b * C + cc) * Hi + 2 * ho) * Wi + 2 * wo) * TPAD;
    const uint8_t* p1 = p0 + TPAD;
    const uint8_t* p2 = p0 + (size_t)Wi * TPAD;
    const uint8_t* p3 = p2 + TPAD;
    uint8_t* sr = sout + (size_t)n * TPAD;
    const IIRC c = iirc_make();
    IIRS st; iirs_init(st);
    for (int t0 = 0; t0 < TREAL; t0 += 4) {
        uint32_t a0 = *(const uint32_t*)(p0 + t0), a1 = *(const uint32_t*)(p1 + t0);
        uint32_t a2 = *(const uint32_t*)(p2 + t0), a3 = *(const uint32_t*)(p3 + t0);
        uint32_t d0 = 0, d1 = 0, d2 = 0, d3 = 0;
        if (t0 >= 100) {
            d0 = *(const uint32_t*)(p0 + t0 - 100); d1 = *(const uint32_t*)(p1 + t0 - 100);
            d2 = *(const uint32_t*)(p2 + t0 - 100); d3 = *(const uint32_t*)(p3 + t0 - 100);
        }
        uint32_t sw = 0;
        #pragma unroll
        for (int j = 0; j < 4; ++j) {
            int sh = 8 * j;
            int cnt  = (int)(((a0 >> sh) & 255u) + ((a1 >> sh) & 255u) +
                             ((a2 >> sh) & 255u) + ((a3 >> sh) & 255u));
            int cntd = (int)(((d0 >> sh) & 255u) + ((d1 >> sh) & 255u) +
                             ((d2 >> sh) & 255u) + ((d3 >> sh) & 255u));
            double x  = POOL_W * (double)cnt;
            double xd = POOL_W * (double)cntd;
            if (iir_step(c, st, x, xd)) sw |= 1u << sh;
        }
        *(uint32_t*)(sr + t0) = sw;
    }
    #pragma unroll
    for (int t0 = TREAL; t0 < TPAD; t0 += 4) *(uint32_t*)(sr + t0) = 0;
}

// ---------------------------------------------------------------------------
// Dense partials: grid (5, Bg, 16).  Writes partial[p][GLOBAL row][t] so the
// final scan runs ONCE after all groups (round-8 bottleneck: 16 tiny serial
// psp_out launches = 4 ms).
// ---------------------------------------------------------------------------
__global__ __launch_bounds__(256) void dense_partial_kernel(
    const uint8_t* __restrict__ s5, const float* __restrict__ Wf,
    double* __restrict__ partial, int b0)
{
    const int tc = blockIdx.x, b = blockIdx.y, p = blockIdx.z;
    const int tid = threadIdx.x;
    const int tl = tid & 63, slot = tid >> 6;
    const int t = tc * 64 + tl;
    const int i0 = p * 256 + slot * 64;
    double acc[10];
    #pragma unroll
    for (int o = 0; o < 10; ++o) acc[o] = 0.0;
    const uint8_t* sp = s5 + ((size_t)b * 4096 + i0) * TPAD + t;
    for (int i = 0; i < 64; ++i) {
        float f = (float)sp[(size_t)i * TPAD];
        if (__any(f != 0.f)) {
            #pragma unroll
            for (int o = 0; o < 10; ++o)
                acc[o] = fma((double)Wf[o * 4096 + i0 + i], (double)f, acc[o]);
        }
    }
    __shared__ double red[4][64][10];
    #pragma unroll
    for (int o = 0; o < 10; ++o) red[slot][tl][o] = acc[o];
    __syncthreads();
    if (slot == 0) {
        #pragma unroll
        for (int o = 0; o < 10; ++o) {
            double v = ((red[0][tl][o] + red[1][tl][o]) + red[2][tl][o]) + red[3][tl][o];
            partial[((size_t)p * 160 + (size_t)(b0 + b) * 10 + o) * TPAD + t] = v;
        }
    }
}

// ---------------------------------------------------------------------------
// Final: ONE launch, block per (b,o) row (160 blocks x 320 thr).
// t-parallel 16-partial sum into LDS; lane-0 IIR scan from LDS; coalesced
// output write by all lanes.
// ---------------------------------------------------------------------------
__global__ __launch_bounds__(320) void psp_out_final_kernel(
    const double* __restrict__ partial, void* __restrict__ out,
    const int* __restrict__ flag)
{
    __shared__ double xs[TPAD];
    __shared__ uint8_t sb[TREAL];
    const int n = blockIdx.x;      // global (b*10+o) row, 0..159
    const int t = threadIdx.x;     // 0..319
    double v = 0.0;
    #pragma unroll
    for (int p = 0; p < 16; ++p)   // ascending p: matches round-8 validated order
        v += partial[((size_t)p * 160 + n) * TPAD + t];
    xs[t] = v;
    __syncthreads();
    if (t == 0) {
        const IIRC c = iirc_make();
        IIRS st; iirs_init(st);
        for (int i = 0; i < TREAL; ++i) {
            double xd = (i >= 100) ? xs[i - 100] : 0.0;
            sb[i] = iir_step(c, st, xs[i], xd) ? 1 : 0;
        }
    }
    __syncthreads();
    if (t < TREAL) {
        size_t e = (size_t)n * TREAL + t;
        if (*flag) ((uint16_t*)out)[e] = sb[t] ? 0x3F80 : 0;
        else       ((float*)out)[e]    = sb[t] ? 1.0f : 0.0f;
    }
}

// ---------------------------------------------------------------------------
__global__ __launch_bounds__(256) void fill_kernel(float* __restrict__ out, int n, float v)
{
    int i = blockIdx.x * 256 + threadIdx.x;
    if (i < n) out[i] = v;
}

// ---------------------------------------------------------------------------
static inline size_t alignup(size_t x) { return (x + 255) & ~(size_t)255; }

extern "C" void kernel_launch(void* const* d_in, const int* in_sizes, int n_in,
                              void* d_out, int out_size, void* d_ws, size_t ws_size,
                              hipStream_t stream)
{
    if (n_in != 5 || in_sizes[0] != 16 * 2 * 34 * 34 * 300 || in_sizes[1] != 800 ||
        in_sizes[2] != 4608 || in_sizes[3] != 18432 || in_sizes[4] != 40960 ||
        out_size != 16 * 10 * 300) {
        fill_kernel<<<(out_size + 255) / 256, 256, 0, stream>>>((float*)d_out, out_size, 2.0e5f);
        return;
    }

    const int NW[4] = {800, 4608, 18432, 40960};
    const size_t flag_sz = alignup(sizeof(int));
    const size_t wf32_sz = alignup((size_t)(800 + 4608 + 18432 + 40960) * 4);
    const size_t sin8_sz = alignup((size_t)16 * 2 * 34 * 34 * TPAD);
    const size_t dpart_sz = alignup((size_t)16 * 160 * TPAD * 8);   // all batches

    int G = -1;
    const int cand[5] = {1, 2, 4, 8, 16};
    for (int k = 0; k < 5; ++k) {
        int g = cand[k];
        int bg = 16 / g;
        size_t need = flag_sz + wf32_sz + sin8_sz + dpart_sz
            + alignup((size_t)bg * 16384 * TPAD * 8)        // z (f64, max = L1)
            + alignup((size_t)bg * 16384 * TPAD)            // spikes A
            + alignup((size_t)bg * 4096 * TPAD);            // spikes B
        if (need <= ws_size) { G = g; break; }
    }
    if (G < 0) {
        fill_kernel<<<(out_size + 255) / 256, 256, 0, stream>>>((float*)d_out, out_size, 1.0e5f);
        return;
    }
    const int Bg = 16 / G;

    char* base = (char*)d_ws;
    int* flag = (int*)base;          base += flag_sz;
    float* wf32 = (float*)base;      base += wf32_sz;
    uint8_t* sin8 = (uint8_t*)base;  base += sin8_sz;
    double* dpart = (double*)base;   base += dpart_sz;
    double* z64 = (double*)base;     base += alignup((size_t)Bg * 16384 * TPAD * 8);
    uint8_t* sA = (uint8_t*)base;    base += alignup((size_t)Bg * 16384 * TPAD);
    uint8_t* sB = (uint8_t*)base;

    detect_kernel<<<1, 64, 0, stream>>>((const uint16_t*)d_in[1], flag);
    float* Wf32[4];
    {
        size_t off = 0;
        for (int i = 0; i < 4; ++i) {
            Wf32[i] = wf32 + off;
            wcvt_kernel<<<(NW[i] + 255) / 256, 256, 0, stream>>>(d_in[1 + i], Wf32[i], NW[i], flag);
            off += NW[i];
        }
    }
    convert_kernel<<<16 * 2 * 34 * 34, 320, 0, stream>>>(d_in[0], sin8, flag);

    for (int g = 0; g < G; ++g) {
        const int b0 = g * Bg;
        const int N1 = Bg * 16 * 32 * 32;
        const int N2 = Bg * 16 * 16 * 16;
        const int N3 = Bg * 32 * 16 * 16;
        const int N4 = Bg * 32 * 8 * 8;
        const int N5 = Bg * 64 * 8 * 8;

        // L1: conv 2->16, 5x5 pad1, 34->32
        conv_kernel<2, 2, 16, 5, 34, 34, 1, 4, 4><<<dim3(32, 4, Bg * 5), 256, 0, stream>>>(
            sin8 + (size_t)b0 * 2 * 34 * 34 * TPAD, Wf32[0], z64, 16);
        psp_iir_kernel<<<(N1 + 255) / 256, 256, 0, stream>>>(z64, sA, N1);

        // L2: fused pool+psp 32->16
        pool_psp_iir_kernel<16, 32><<<(N2 + 255) / 256, 256, 0, stream>>>(sA, sB, N2);

        // L3: conv 16->32, 3x3 pad1, 16->16
        conv_kernel<16, 8, 32, 3, 16, 16, 2, 4, 4><<<dim3(16, 4, Bg * 5), 256, 0, stream>>>(
            sB, Wf32[1], z64, 32);
        psp_iir_kernel<<<(N3 + 255) / 256, 256, 0, stream>>>(z64, sA, N3);

        // L4: fused pool+psp 16->8
        pool_psp_iir_kernel<32, 16><<<(N4 + 255) / 256, 256, 0, stream>>>(sA, sB, N4);

        // L5: conv 32->64, 3x3 pad1, 8->8
        conv_kernel<32, 8, 32, 3, 8, 8, 2, 4, 2><<<dim3(8, 4, Bg * 5), 256, 0, stream>>>(
            sB, Wf32[2], z64, 64);
        psp_iir_kernel<<<(N5 + 255) / 256, 256, 0, stream>>>(z64, sA, N5);

        // L6: dense partials (global-batch indexed)
        dense_partial_kernel<<<dim3(5, Bg, 16), 256, 0, stream>>>(sA, Wf32[3], dpart, b0);
    }

    // single final scan for all 160 output rows
    psp_out_final_kernel<<<160, 320, 0, stream>>>(dpart, d_out, flag);
}